// Round 1
// baseline (2973.676 us; speedup 1.0000x reference)
//
#include <hip/hip_runtime.h>
#include <math.h>

#ifndef NEG_SLOPE
#define NEG_SLOPE 0.2f
#endif

// ---------------------------------------------------------------------------
// Edge-index dtype sniffer: if the buffer is int64 little-endian with values
// < 2^31, every odd 32-bit word is 0. For int32 layout those words are real
// node ids (random in [0,1e5)); P(256 consecutive zeros) ~ 0.
// ---------------------------------------------------------------------------
__global__ void detect_i64(const int* __restrict__ ei, int* __restrict__ flag) {
    if (threadIdx.x == 0 && blockIdx.x == 0) {
        int z = 1;
        for (int i = 0; i < 256; ++i) {
            if (ei[2 * i + 1] != 0) { z = 0; break; }
        }
        *flag = z;
    }
}

__device__ __forceinline__ void get_edge(const void* ei, int is64, int e, int E,
                                         int& s, int& d) {
    if (e >= E) { s = e - E; d = s; return; }   // self-loop
    if (is64) {
        const long long* p = (const long long*)ei;
        s = (int)p[e];
        d = (int)p[(long long)E + e];
    } else {
        const int* p = (const int*)ei;
        s = p[e];
        d = p[E + e];
    }
}

// ---------------------------------------------------------------------------
// Fused GEMM + attention coefficients:
//   H = A @ W          (A: [N,64], W: [64,F])
//   as_out = H @ a_src, ad_out = H @ a_dst
// Block = 256 threads, TPR threads per row, R = 256/TPR rows per block.
// ---------------------------------------------------------------------------
template <int F, int TPR>
__global__ __launch_bounds__(256) void gemm_att(
    const float* __restrict__ A, const float* __restrict__ W,
    const float* __restrict__ avs, const float* __restrict__ avd,
    float* __restrict__ H, float* __restrict__ as_out, float* __restrict__ ad_out,
    int Nrows) {
    constexpr int K = 64;
    constexpr int R = 256 / TPR;   // rows per block
    constexpr int C = F / TPR;     // features per thread
    __shared__ float sW[K * F];
    __shared__ float sA[R * (K + 4)];   // stride 68: 2-way bank aliasing (free)
    __shared__ float sas[F], sad[F];

    const int t = threadIdx.x;
    for (int i = t; i < K * F / 4; i += 256)
        ((float4*)sW)[i] = ((const float4*)W)[i];
    for (int i = t; i < F; i += 256) { sas[i] = avs[i]; sad[i] = avd[i]; }

    const int base = blockIdx.x * R;
    for (int i = t; i < R * (K / 4); i += 256) {
        int row = i >> 4;          // K/4 == 16
        int c4  = i & 15;
        float4 v = make_float4(0.f, 0.f, 0.f, 0.f);
        if (base + row < Nrows)
            v = ((const float4*)(A + (size_t)(base + row) * K))[c4];
        float* dp = &sA[row * (K + 4) + c4 * 4];
        dp[0] = v.x; dp[1] = v.y; dp[2] = v.z; dp[3] = v.w;
    }
    __syncthreads();

    const int r  = t / TPR;
    const int f0 = (t % TPR) * C;
    float acc[C];
#pragma unroll
    for (int j = 0; j < C; ++j) acc[j] = 0.f;
    const float* sa = &sA[r * (K + 4)];
#pragma unroll
    for (int k = 0; k < K; ++k) {
        float av = sa[k];
        const float* w = &sW[k * F + f0];
#pragma unroll
        for (int j = 0; j < C; ++j) acc[j] += av * w[j];
    }

    float ps = 0.f, pd = 0.f;
#pragma unroll
    for (int j = 0; j < C; ++j) { ps += acc[j] * sas[f0 + j]; pd += acc[j] * sad[f0 + j]; }
#pragma unroll
    for (int off = 1; off < TPR; off <<= 1) {
        ps += __shfl_xor(ps, off);
        pd += __shfl_xor(pd, off);
    }

    const int row = base + r;
    if (row < Nrows) {
        if ((t % TPR) == 0) { as_out[row] = ps; ad_out[row] = pd; }
        float* hp = H + (size_t)row * F + f0;
#pragma unroll
        for (int j = 0; j < C; ++j) hp[j] = acc[j];
    }
}

// ---------------------------------------------------------------------------
// Pass 1 over edges: e = leaky_relu(as[src]+ad[dst]); segment max via
// monotone uint encoding + atomicMax.
// ---------------------------------------------------------------------------
__global__ __launch_bounds__(256) void edge_logits(
    const void* __restrict__ ei, const int* __restrict__ flag,
    const float* __restrict__ as_, const float* __restrict__ ad_,
    float* __restrict__ ebuf, unsigned* __restrict__ menc, int E, int Etot) {
    int e = blockIdx.x * 256 + threadIdx.x;
    if (e >= Etot) return;
    int s, d;
    get_edge(ei, *flag, e, E, s, d);
    float v = as_[s] + ad_[d];
    v = v > 0.f ? v : NEG_SLOPE * v;
    ebuf[e] = v;
    unsigned u = __float_as_uint(v);
    u = (u & 0x80000000u) ? ~u : (u | 0x80000000u);
    atomicMax(&menc[d], u);
}

// Pass 2: exp(e - m[dst]) and segment sum.
__global__ __launch_bounds__(256) void edge_exp(
    const void* __restrict__ ei, const int* __restrict__ flag,
    float* __restrict__ ebuf, const unsigned* __restrict__ menc,
    float* __restrict__ ssum, int E, int Etot) {
    int e = blockIdx.x * 256 + threadIdx.x;
    if (e >= Etot) return;
    int s, d;
    get_edge(ei, *flag, e, E, s, d);
    unsigned u = menc[d];
    float mx = (u & 0x80000000u) ? __uint_as_float(u & 0x7FFFFFFFu)
                                 : __uint_as_float(~u);
    float w = __expf(ebuf[e] - mx);
    ebuf[e] = w;
    unsafeAtomicAdd(&ssum[d], w);
}

// Pass 3: out[dst] += (ebuf[e]/(s[dst]+eps)) * H[src].  One thread per
// (edge, float4-chunk); chunk is the fast index for coalescing.
template <int F>
__global__ __launch_bounds__(256) void edge_aggregate(
    const void* __restrict__ ei, const int* __restrict__ flag,
    const float* __restrict__ ebuf, const float* __restrict__ ssum,
    const float* __restrict__ H, float* __restrict__ out, int E, int Etot) {
    constexpr int QF = F / 4;
    long long idx = (long long)blockIdx.x * 256 + threadIdx.x;
    if (idx >= (long long)Etot * QF) return;
    int e = (int)(idx / QF);
    int q = (int)(idx % QF);
    int s, d;
    get_edge(ei, *flag, e, E, s, d);
    float alpha = ebuf[e] / (ssum[d] + 1e-16f);
    float4 hv = ((const float4*)(H + (size_t)s * F))[q];
    float* op = out + (size_t)d * F + q * 4;
    unsafeAtomicAdd(op + 0, alpha * hv.x);
    unsafeAtomicAdd(op + 1, alpha * hv.y);
    unsafeAtomicAdd(op + 2, alpha * hv.z);
    unsafeAtomicAdd(op + 3, alpha * hv.w);
}

// Layer-1 epilogue: agg = relu(agg + b1)   (64 features, float4-wise)
__global__ __launch_bounds__(256) void bias_relu64(
    float4* __restrict__ a, const float* __restrict__ b, long long nq) {
    long long i = (long long)blockIdx.x * 256 + threadIdx.x;
    if (i >= nq) return;
    float4 bv = ((const float4*)b)[i & 15];
    float4 v = a[i];
    v.x = fmaxf(v.x + bv.x, 0.f);
    v.y = fmaxf(v.y + bv.y, 0.f);
    v.z = fmaxf(v.z + bv.z, 0.f);
    v.w = fmaxf(v.w + bv.w, 0.f);
    a[i] = v;
}

// Final: out = log_softmax(out + b2) over 40 features; one wave per row.
__global__ __launch_bounds__(256) void logsoftmax40(
    float* __restrict__ out, const float* __restrict__ b, int N) {
    int wid  = blockIdx.x * 4 + (threadIdx.x >> 6);
    int lane = threadIdx.x & 63;
    if (wid >= N) return;
    float* rowp = out + (size_t)wid * 40;
    float val = 0.f, v = -3.0e38f;
    if (lane < 40) { val = rowp[lane] + b[lane]; v = val; }
    float mx = v;
    for (int off = 32; off; off >>= 1) mx = fmaxf(mx, __shfl_xor(mx, off));
    float ex = (lane < 40) ? __expf(val - mx) : 0.f;
    float sm = ex;
    for (int off = 32; off; off >>= 1) sm += __shfl_xor(sm, off);
    float ls = logf(sm);
    if (lane < 40) rowp[lane] = val - mx - ls;
}

extern "C" void kernel_launch(void* const* d_in, const int* in_sizes, int n_in,
                              void* d_out, int out_size, void* d_ws, size_t ws_size,
                              hipStream_t stream) {
    const float* x   = (const float*)d_in[0];
    const void*  ei  = d_in[1];
    const float* W1  = (const float*)d_in[2];
    const float* as1 = (const float*)d_in[3];
    const float* ad1 = (const float*)d_in[4];
    const float* b1  = (const float*)d_in[5];
    const float* W2  = (const float*)d_in[6];
    const float* as2 = (const float*)d_in[7];
    const float* ad2 = (const float*)d_in[8];
    const float* b2  = (const float*)d_in[9];
    float* out = (float*)d_out;

    const int N    = in_sizes[0] / 64;
    const int E    = in_sizes[1] / 2;
    const int Etot = E + N;

    float* ws = (float*)d_ws;
    float* h    = ws;  ws += (size_t)N * 64;
    float* agg1 = ws;  ws += (size_t)N * 64;
    float* ebuf = ws;  ws += Etot;
    float* asn  = ws;  ws += N;
    float* adn  = ws;  ws += N;
    unsigned* menc = (unsigned*)ws;  ws += N;   // menc and ssum adjacent
    float* ssum = ws;  ws += N;
    int* flag   = (int*)ws;

    detect_i64<<<1, 64, 0, stream>>>((const int*)ei, flag);

    const int EB = (Etot + 255) / 256;

    // ---- layer 1 (F = 64) ----
    hipMemsetAsync(menc, 0, (size_t)N * 2 * sizeof(float), stream);  // menc+ssum
    hipMemsetAsync(agg1, 0, (size_t)N * 64 * sizeof(float), stream);
    gemm_att<64, 4><<<(N + 63) / 64, 256, 0, stream>>>(x, W1, as1, ad1, h, asn, adn, N);
    edge_logits<<<EB, 256, 0, stream>>>(ei, flag, asn, adn, ebuf, menc, E, Etot);
    edge_exp<<<EB, 256, 0, stream>>>(ei, flag, ebuf, menc, ssum, E, Etot);
    {
        long long tot = (long long)Etot * 16;
        edge_aggregate<64><<<(int)((tot + 255) / 256), 256, 0, stream>>>(
            ei, flag, ebuf, ssum, h, agg1, E, Etot);
    }
    {
        long long nq = (long long)N * 16;
        bias_relu64<<<(int)((nq + 255) / 256), 256, 0, stream>>>((float4*)agg1, b1, nq);
    }

    // ---- layer 2 (F = 40) ----
    hipMemsetAsync(menc, 0, (size_t)N * 2 * sizeof(float), stream);
    hipMemsetAsync(out, 0, (size_t)N * 40 * sizeof(float), stream);
    gemm_att<40, 4><<<(N + 63) / 64, 256, 0, stream>>>(agg1, W2, as2, ad2, h, asn, adn, N);
    edge_logits<<<EB, 256, 0, stream>>>(ei, flag, asn, adn, ebuf, menc, E, Etot);
    edge_exp<<<EB, 256, 0, stream>>>(ei, flag, ebuf, menc, ssum, E, Etot);
    {
        long long tot = (long long)Etot * 10;
        edge_aggregate<40><<<(int)((tot + 255) / 256), 256, 0, stream>>>(
            ei, flag, ebuf, ssum, h, out, E, Etot);
    }
    logsoftmax40<<<(N + 3) / 4, 256, 0, stream>>>(out, b2, N);
}

// Round 2
// 552.945 us; speedup vs baseline: 5.3779x; 5.3779x over previous
//
#include <hip/hip_runtime.h>
#include <math.h>

#ifndef NEG_SLOPE
#define NEG_SLOPE 0.2f
#endif

// ---------------------------------------------------------------------------
// Edge-index dtype sniffer (int64 vs int32 layout). Deterministic per input.
// ---------------------------------------------------------------------------
__global__ void detect_i64(const int* __restrict__ ei, int* __restrict__ flag) {
    if (threadIdx.x == 0 && blockIdx.x == 0) {
        int z = 1;
        for (int i = 0; i < 256; ++i) {
            if (ei[2 * i + 1] != 0) { z = 0; break; }
        }
        *flag = z;
    }
}

__device__ __forceinline__ void get_edge(const void* ei, int is64, int e, int E,
                                         int& s, int& d) {
    if (e >= E) { s = e - E; d = s; return; }   // self-loop
    if (is64) {
        const long long* p = (const long long*)ei;
        s = (int)p[e];
        d = (int)p[(long long)E + e];
    } else {
        const int* p = (const int*)ei;
        s = p[e];
        d = p[E + e];
    }
}

// ---------------------------------------------------------------------------
// Fused GEMM + attention coefficients (unchanged from R1; not a hot spot yet).
// ---------------------------------------------------------------------------
template <int F, int TPR>
__global__ __launch_bounds__(256) void gemm_att(
    const float* __restrict__ A, const float* __restrict__ W,
    const float* __restrict__ avs, const float* __restrict__ avd,
    float* __restrict__ H, float* __restrict__ as_out, float* __restrict__ ad_out,
    int Nrows) {
    constexpr int K = 64;
    constexpr int R = 256 / TPR;
    constexpr int C = F / TPR;
    __shared__ float sW[K * F];
    __shared__ float sA[R * (K + 4)];
    __shared__ float sas[F], sad[F];

    const int t = threadIdx.x;
    for (int i = t; i < K * F / 4; i += 256)
        ((float4*)sW)[i] = ((const float4*)W)[i];
    for (int i = t; i < F; i += 256) { sas[i] = avs[i]; sad[i] = avd[i]; }

    const int base = blockIdx.x * R;
    for (int i = t; i < R * (K / 4); i += 256) {
        int row = i >> 4;
        int c4  = i & 15;
        float4 v = make_float4(0.f, 0.f, 0.f, 0.f);
        if (base + row < Nrows)
            v = ((const float4*)(A + (size_t)(base + row) * K))[c4];
        float* dp = &sA[row * (K + 4) + c4 * 4];
        dp[0] = v.x; dp[1] = v.y; dp[2] = v.z; dp[3] = v.w;
    }
    __syncthreads();

    const int r  = t / TPR;
    const int f0 = (t % TPR) * C;
    float acc[C];
#pragma unroll
    for (int j = 0; j < C; ++j) acc[j] = 0.f;
    const float* sa = &sA[r * (K + 4)];
#pragma unroll
    for (int k = 0; k < K; ++k) {
        float av = sa[k];
        const float* w = &sW[k * F + f0];
#pragma unroll
        for (int j = 0; j < C; ++j) acc[j] += av * w[j];
    }

    float ps = 0.f, pd = 0.f;
#pragma unroll
    for (int j = 0; j < C; ++j) { ps += acc[j] * sas[f0 + j]; pd += acc[j] * sad[f0 + j]; }
#pragma unroll
    for (int off = 1; off < TPR; off <<= 1) {
        ps += __shfl_xor(ps, off);
        pd += __shfl_xor(pd, off);
    }

    const int row = base + r;
    if (row < Nrows) {
        if ((t % TPR) == 0) { as_out[row] = ps; ad_out[row] = pd; }
        float* hp = H + (size_t)row * F + f0;
#pragma unroll
        for (int j = 0; j < C; ++j) hp[j] = acc[j];
    }
}

// ---------------------------------------------------------------------------
// CSR build: histogram -> scan (3 kernels) -> scatter.
// ---------------------------------------------------------------------------
__global__ __launch_bounds__(256) void edge_hist(
    const void* __restrict__ ei, const int* __restrict__ flag,
    int* __restrict__ counts, int E, int Etot) {
    int e = blockIdx.x * 256 + threadIdx.x;
    if (e >= Etot) return;
    int s, d;
    get_edge(ei, *flag, e, E, s, d);
    atomicAdd(&counts[d], 1);
}

// Per-block exclusive scan over chunks of 2048; block totals to bsum.
__global__ __launch_bounds__(256) void scan1(
    const int* __restrict__ in, int* __restrict__ out,
    int* __restrict__ bsum, int n) {
    __shared__ int lds[256];
    const int base = blockIdx.x * 2048;
    const int t = threadIdx.x;
    int v[8];
    int s = 0;
#pragma unroll
    for (int j = 0; j < 8; ++j) {
        int idx = base + t * 8 + j;
        v[j] = (idx < n) ? in[idx] : 0;
        s += v[j];
    }
    lds[t] = s;
    __syncthreads();
    int x = s;
    for (int off = 1; off < 256; off <<= 1) {
        int y = (t >= off) ? lds[t - off] : 0;
        __syncthreads();
        x += y;
        lds[t] = x;
        __syncthreads();
    }
    if (t == 255) bsum[blockIdx.x] = x;
    int run = x - s;   // exclusive prefix within block
#pragma unroll
    for (int j = 0; j < 8; ++j) {
        int idx = base + t * 8 + j;
        if (idx < n) out[idx] = run;
        run += v[j];
    }
}

__global__ void scan2(int* __restrict__ bsum, int nb, int* __restrict__ total_out) {
    if (threadIdx.x == 0 && blockIdx.x == 0) {
        int run = 0;
        for (int i = 0; i < nb; ++i) { int t = bsum[i]; bsum[i] = run; run += t; }
        *total_out = run;   // = row_ptr[N]
    }
}

__global__ __launch_bounds__(256) void scan_add(
    int* __restrict__ out, const int* __restrict__ bsum_ex, int n) {
    int idx = blockIdx.x * 256 + threadIdx.x;
    if (idx < n) out[idx] += bsum_ex[idx >> 11];
}

__global__ __launch_bounds__(256) void edge_scatter(
    const void* __restrict__ ei, const int* __restrict__ flag,
    const int* __restrict__ row_ptr, int* __restrict__ fill,
    int* __restrict__ csr_src, int E, int Etot) {
    int e = blockIdx.x * 256 + threadIdx.x;
    if (e >= Etot) return;
    int s, d;
    get_edge(ei, *flag, e, E, s, d);
    int pos = row_ptr[d] + atomicAdd(&fill[d], 1);
    csr_src[pos] = s;
}

// ---------------------------------------------------------------------------
// Fused per-dst GAT aggregation: one wave per dst node.
//   pass 1: segment max of leaky_relu(as[src]+ad[dst])
//   pass 2: w = exp(logit - m); acc[f] += w * H[src][f]; S += w
//   epilogue: out = acc/(S+eps) + bias  (+relu or +log_softmax)
// No atomics; one coalesced F-float write per node.
// ---------------------------------------------------------------------------
template <int F, bool RELU, bool LSM>
__global__ __launch_bounds__(256) void gat_aggregate(
    const int* __restrict__ row_ptr, const int* __restrict__ csr_src,
    const float* __restrict__ asn, const float* __restrict__ adn,
    const float* __restrict__ H, const float* __restrict__ bias,
    float* __restrict__ out, int N) {
    int wid  = blockIdx.x * 4 + (threadIdx.x >> 6);
    int lane = threadIdx.x & 63;
    if (wid >= N) return;
    const int r0 = row_ptr[wid], r1 = row_ptr[wid + 1];
    const float add = adn[wid];

    // pass 1: segment max
    float m = -3.0e38f;
    for (int i = r0 + lane; i < r1; i += 64) {
        int s = csr_src[i];
        float v = asn[s] + add;
        v = v > 0.f ? v : NEG_SLOPE * v;
        m = fmaxf(m, v);
    }
    for (int off = 32; off; off >>= 1) m = fmaxf(m, __shfl_xor(m, off));

    // pass 2: fused exp-sum + aggregation
    float acc = 0.f;
    float Ssum = 0.f;
    for (int base = r0; base < r1; base += 64) {
        int cnt = r1 - base;
        if (cnt > 64) cnt = 64;
        int s = 0;
        float w = 0.f;
        if (lane < cnt) {
            s = csr_src[base + lane];
            float v = asn[s] + add;
            v = v > 0.f ? v : NEG_SLOPE * v;
            w = __expf(v - m);
        }
        Ssum += w;
        for (int j = 0; j < cnt; ++j) {
            int   sj = __shfl(s, j);
            float wj = __shfl(w, j);
            float hv = (lane < F) ? H[(size_t)sj * F + lane] : 0.f;
            acc += wj * hv;
        }
    }
    for (int off = 32; off; off >>= 1) Ssum += __shfl_xor(Ssum, off);
    float r = acc / (Ssum + 1e-16f);

    if (LSM) {
        float val = 0.f, vv = -3.0e38f;
        if (lane < F) { val = r + bias[lane]; vv = val; }
        float mx = vv;
        for (int off = 32; off; off >>= 1) mx = fmaxf(mx, __shfl_xor(mx, off));
        float ex = (lane < F) ? __expf(val - mx) : 0.f;
        float sm = ex;
        for (int off = 32; off; off >>= 1) sm += __shfl_xor(sm, off);
        float ls = logf(sm);
        if (lane < F) out[(size_t)wid * F + lane] = val - mx - ls;
    } else {
        if (lane < F) {
            float v2 = r + bias[lane];
            if (RELU) v2 = fmaxf(v2, 0.f);
            out[(size_t)wid * F + lane] = v2;
        }
    }
}

extern "C" void kernel_launch(void* const* d_in, const int* in_sizes, int n_in,
                              void* d_out, int out_size, void* d_ws, size_t ws_size,
                              hipStream_t stream) {
    const float* x   = (const float*)d_in[0];
    const void*  ei  = d_in[1];
    const float* W1  = (const float*)d_in[2];
    const float* as1 = (const float*)d_in[3];
    const float* ad1 = (const float*)d_in[4];
    const float* b1  = (const float*)d_in[5];
    const float* W2  = (const float*)d_in[6];
    const float* as2 = (const float*)d_in[7];
    const float* ad2 = (const float*)d_in[8];
    const float* b2  = (const float*)d_in[9];
    float* out = (float*)d_out;

    const int N    = in_sizes[0] / 64;
    const int E    = in_sizes[1] / 2;
    const int Etot = E + N;

    float* ws = (float*)d_ws;
    float* h    = ws;              ws += (size_t)N * 64;
    float* agg1 = ws;              ws += (size_t)N * 64;
    float* asn  = ws;              ws += N;
    float* adn  = ws;              ws += N;
    int* counts = (int*)ws;        ws += N;
    int* row_ptr = (int*)ws;       ws += N + 1;
    int* fill   = (int*)ws;        ws += N;
    int* csr_src = (int*)ws;       ws += Etot;
    int* bsum   = (int*)ws;        ws += 256;
    int* flag   = (int*)ws;

    const int EB = (Etot + 255) / 256;
    const int NB = (N + 255) / 256;
    const int numScanBlocks = (N + 2047) / 2048;

    detect_i64<<<1, 64, 0, stream>>>((const int*)ei, flag);

    // ---- CSR build (once; shared by both layers) ----
    hipMemsetAsync(counts, 0, (size_t)N * sizeof(int), stream);
    hipMemsetAsync(fill, 0, (size_t)N * sizeof(int), stream);
    edge_hist<<<EB, 256, 0, stream>>>(ei, flag, counts, E, Etot);
    scan1<<<numScanBlocks, 256, 0, stream>>>(counts, row_ptr, bsum, N);
    scan2<<<1, 64, 0, stream>>>(bsum, numScanBlocks, &row_ptr[N]);
    scan_add<<<NB, 256, 0, stream>>>(row_ptr, bsum, N);
    edge_scatter<<<EB, 256, 0, stream>>>(ei, flag, row_ptr, fill, csr_src, E, Etot);

    const int AGG_B = (N + 3) / 4;

    // ---- layer 1 (F = 64): out = relu(agg + b1) ----
    gemm_att<64, 4><<<(N + 63) / 64, 256, 0, stream>>>(x, W1, as1, ad1, h, asn, adn, N);
    gat_aggregate<64, true, false><<<AGG_B, 256, 0, stream>>>(
        row_ptr, csr_src, asn, adn, h, b1, agg1, N);

    // ---- layer 2 (F = 40): out = log_softmax(agg + b2) ----
    gemm_att<40, 4><<<(N + 63) / 64, 256, 0, stream>>>(agg1, W2, as2, ad2, h, asn, adn, N);
    gat_aggregate<40, false, true><<<AGG_B, 256, 0, stream>>>(
        row_ptr, csr_src, asn, adn, h, b2, out, N);
}

// Round 3
// 467.952 us; speedup vs baseline: 6.3547x; 1.1816x over previous
//
#include <hip/hip_runtime.h>
#include <math.h>

#ifndef NEG_SLOPE
#define NEG_SLOPE 0.2f
#endif

// ---------------------------------------------------------------------------
// Edge-index dtype sniffer (int64 vs int32 layout). One wave, ballot.
// ---------------------------------------------------------------------------
__global__ void detect_i64(const int* __restrict__ ei, int* __restrict__ flag) {
    int lane = threadIdx.x & 63;
    int bad = 0;
    for (int j = 0; j < 4; ++j) bad |= (ei[2 * (lane * 4 + j) + 1] != 0);
    unsigned long long m = __ballot(bad);
    if (lane == 0) *flag = (m == 0ull) ? 1 : 0;
}

__device__ __forceinline__ void get_edge(const void* ei, int is64, int e, int E,
                                         int& s, int& d) {
    if (e >= E) { s = e - E; d = s; return; }   // self-loop
    if (is64) {
        const long long* p = (const long long*)ei;
        s = (int)p[e];
        d = (int)p[(long long)E + e];
    } else {
        const int* p = (const int*)ei;
        s = p[e];
        d = p[E + e];
    }
}

// ---------------------------------------------------------------------------
// Fused GEMM + attention coefficients.
// ---------------------------------------------------------------------------
template <int F, int TPR>
__global__ __launch_bounds__(256) void gemm_att(
    const float* __restrict__ A, const float* __restrict__ W,
    const float* __restrict__ avs, const float* __restrict__ avd,
    float* __restrict__ H, float* __restrict__ as_out, float* __restrict__ ad_out,
    int Nrows) {
    constexpr int K = 64;
    constexpr int R = 256 / TPR;
    constexpr int C = F / TPR;
    __shared__ float sW[K * F];
    __shared__ float sA[R * (K + 4)];
    __shared__ float sas[F], sad[F];

    const int t = threadIdx.x;
    for (int i = t; i < K * F / 4; i += 256)
        ((float4*)sW)[i] = ((const float4*)W)[i];
    for (int i = t; i < F; i += 256) { sas[i] = avs[i]; sad[i] = avd[i]; }

    const int base = blockIdx.x * R;
    for (int i = t; i < R * (K / 4); i += 256) {
        int row = i >> 4;
        int c4  = i & 15;
        float4 v = make_float4(0.f, 0.f, 0.f, 0.f);
        if (base + row < Nrows)
            v = ((const float4*)(A + (size_t)(base + row) * K))[c4];
        float* dp = &sA[row * (K + 4) + c4 * 4];
        dp[0] = v.x; dp[1] = v.y; dp[2] = v.z; dp[3] = v.w;
    }
    __syncthreads();

    const int r  = t / TPR;
    const int f0 = (t % TPR) * C;
    float acc[C];
#pragma unroll
    for (int j = 0; j < C; ++j) acc[j] = 0.f;
    const float* sa = &sA[r * (K + 4)];
#pragma unroll
    for (int k = 0; k < K; ++k) {
        float av = sa[k];
        const float* w = &sW[k * F + f0];
#pragma unroll
        for (int j = 0; j < C; ++j) acc[j] += av * w[j];
    }

    float ps = 0.f, pd = 0.f;
#pragma unroll
    for (int j = 0; j < C; ++j) { ps += acc[j] * sas[f0 + j]; pd += acc[j] * sad[f0 + j]; }
#pragma unroll
    for (int off = 1; off < TPR; off <<= 1) {
        ps += __shfl_xor(ps, off);
        pd += __shfl_xor(pd, off);
    }

    const int row = base + r;
    if (row < Nrows) {
        if ((t % TPR) == 0) { as_out[row] = ps; ad_out[row] = pd; }
        float* hp = H + (size_t)row * F + f0;
#pragma unroll
        for (int j = 0; j < C; ++j) hp[j] = acc[j];
    }
}

// ---------------------------------------------------------------------------
// CSR build: histogram -> scan -> scatter.
// ---------------------------------------------------------------------------
__global__ __launch_bounds__(256) void edge_hist(
    const void* __restrict__ ei, const int* __restrict__ flag,
    int* __restrict__ counts, int E, int Etot) {
    int e = blockIdx.x * 256 + threadIdx.x;
    if (e >= Etot) return;
    int s, d;
    get_edge(ei, *flag, e, E, s, d);
    atomicAdd(&counts[d], 1);
}

__global__ __launch_bounds__(256) void scan1(
    const int* __restrict__ in, int* __restrict__ out,
    int* __restrict__ bsum, int n) {
    __shared__ int lds[256];
    const int base = blockIdx.x * 2048;
    const int t = threadIdx.x;
    int v[8];
    int s = 0;
#pragma unroll
    for (int j = 0; j < 8; ++j) {
        int idx = base + t * 8 + j;
        v[j] = (idx < n) ? in[idx] : 0;
        s += v[j];
    }
    lds[t] = s;
    __syncthreads();
    int x = s;
    for (int off = 1; off < 256; off <<= 1) {
        int y = (t >= off) ? lds[t - off] : 0;
        __syncthreads();
        x += y;
        lds[t] = x;
        __syncthreads();
    }
    if (t == 255) bsum[blockIdx.x] = x;
    int run = x - s;
#pragma unroll
    for (int j = 0; j < 8; ++j) {
        int idx = base + t * 8 + j;
        if (idx < n) out[idx] = run;
        run += v[j];
    }
}

__global__ void scan2(int* __restrict__ bsum, int nb, int* __restrict__ total_out) {
    if (threadIdx.x == 0 && blockIdx.x == 0) {
        int run = 0;
        for (int i = 0; i < nb; ++i) { int t = bsum[i]; bsum[i] = run; run += t; }
        *total_out = run;
    }
}

__global__ __launch_bounds__(256) void scan_add(
    int* __restrict__ out, const int* __restrict__ bsum_ex, int n) {
    int idx = blockIdx.x * 256 + threadIdx.x;
    if (idx < n) out[idx] += bsum_ex[idx >> 11];
}

__global__ __launch_bounds__(256) void edge_scatter(
    const void* __restrict__ ei, const int* __restrict__ flag,
    const int* __restrict__ row_ptr, int* __restrict__ fill,
    int* __restrict__ csr_src, int E, int Etot) {
    int e = blockIdx.x * 256 + threadIdx.x;
    if (e >= Etot) return;
    int s, d;
    get_edge(ei, *flag, e, E, s, d);
    int pos = row_ptr[d] + atomicAdd(&fill[d], 1);
    csr_src[pos] = s;
}

// ---------------------------------------------------------------------------
// Fused per-dst GAT aggregation, one wave per dst node. SINGLE pass:
//   w = exp(leaky(as[src]+ad[dst]))   (softmax shift-invariance: no max pass;
//                                      |logit| <~ 6 so exp is fp32-safe)
//   acc[f] += w * H[src][f]; S += w
//   out = acc/(S+eps) + bias  (+relu or +log_softmax)
// Gather loop software-pipelined: 8 (then 4) independent 256-B loads in
// flight per wave instead of 1 (R2 was latency-bound: VALUBusy 35%, HBM 19%).
// ---------------------------------------------------------------------------
template <int F, bool RELU, bool LSM>
__global__ __launch_bounds__(256) void gat_aggregate(
    const int* __restrict__ row_ptr, const int* __restrict__ csr_src,
    const float* __restrict__ asn, const float* __restrict__ adn,
    const float* __restrict__ H, const float* __restrict__ bias,
    float* __restrict__ out, int N) {
    int wid  = blockIdx.x * 4 + (threadIdx.x >> 6);
    int lane = threadIdx.x & 63;
    if (wid >= N) return;
    const int r0 = row_ptr[wid], r1 = row_ptr[wid + 1];
    const float add = adn[wid];

    float acc = 0.f;
    float Ssum = 0.f;
    for (int base = r0; base < r1; base += 64) {
        int cnt = r1 - base;
        if (cnt > 64) cnt = 64;
        int s = 0;
        float w = 0.f;
        if (lane < cnt) {
            s = csr_src[base + lane];
            float v = asn[s] + add;
            v = v > 0.f ? v : NEG_SLOPE * v;
            w = __expf(v);
        }
        Ssum += w;
        int j = 0;
        for (; j + 8 <= cnt; j += 8) {
            float wj[8], hv[8];
            const float* p[8];
#pragma unroll
            for (int u = 0; u < 8; ++u) {
                int su = __shfl(s, j + u);
                wj[u]  = __shfl(w, j + u);
                p[u]   = H + (size_t)su * F + lane;
            }
#pragma unroll
            for (int u = 0; u < 8; ++u)
                hv[u] = (F == 64 || lane < F) ? p[u][0] : 0.f;
#pragma unroll
            for (int u = 0; u < 8; ++u) acc += wj[u] * hv[u];
        }
        for (; j + 4 <= cnt; j += 4) {
            float wj[4], hv[4];
            const float* p[4];
#pragma unroll
            for (int u = 0; u < 4; ++u) {
                int su = __shfl(s, j + u);
                wj[u]  = __shfl(w, j + u);
                p[u]   = H + (size_t)su * F + lane;
            }
#pragma unroll
            for (int u = 0; u < 4; ++u)
                hv[u] = (F == 64 || lane < F) ? p[u][0] : 0.f;
#pragma unroll
            for (int u = 0; u < 4; ++u) acc += wj[u] * hv[u];
        }
        for (; j < cnt; ++j) {
            int   sj = __shfl(s, j);
            float wj = __shfl(w, j);
            float hv = (F == 64 || lane < F) ? H[(size_t)sj * F + lane] : 0.f;
            acc += wj * hv;
        }
    }
    for (int off = 32; off; off >>= 1) Ssum += __shfl_xor(Ssum, off);
    float r = acc / (Ssum + 1e-16f);

    if (LSM) {
        float val = 0.f, vv = -3.0e38f;
        if (lane < F) { val = r + bias[lane]; vv = val; }
        float mx = vv;
        for (int off = 32; off; off >>= 1) mx = fmaxf(mx, __shfl_xor(mx, off));
        float ex = (lane < F) ? __expf(val - mx) : 0.f;
        float sm = ex;
        for (int off = 32; off; off >>= 1) sm += __shfl_xor(sm, off);
        float ls = logf(sm);
        if (lane < F) out[(size_t)wid * F + lane] = val - mx - ls;
    } else {
        if (lane < F) {
            float v2 = r + bias[lane];
            if (RELU) v2 = fmaxf(v2, 0.f);
            out[(size_t)wid * F + lane] = v2;
        }
    }
}

extern "C" void kernel_launch(void* const* d_in, const int* in_sizes, int n_in,
                              void* d_out, int out_size, void* d_ws, size_t ws_size,
                              hipStream_t stream) {
    const float* x   = (const float*)d_in[0];
    const void*  ei  = d_in[1];
    const float* W1  = (const float*)d_in[2];
    const float* as1 = (const float*)d_in[3];
    const float* ad1 = (const float*)d_in[4];
    const float* b1  = (const float*)d_in[5];
    const float* W2  = (const float*)d_in[6];
    const float* as2 = (const float*)d_in[7];
    const float* ad2 = (const float*)d_in[8];
    const float* b2  = (const float*)d_in[9];
    float* out = (float*)d_out;

    const int N    = in_sizes[0] / 64;
    const int E    = in_sizes[1] / 2;
    const int Etot = E + N;

    float* ws = (float*)d_ws;
    float* h    = ws;              ws += (size_t)N * 64;
    float* agg1 = ws;              ws += (size_t)N * 64;
    float* asn  = ws;              ws += N;
    float* adn  = ws;              ws += N;
    int* counts = (int*)ws;        ws += N;
    int* row_ptr = (int*)ws;       ws += N + 1;
    int* fill   = (int*)ws;        ws += N;
    int* csr_src = (int*)ws;       ws += Etot;
    int* bsum   = (int*)ws;        ws += 256;
    int* flag   = (int*)ws;

    const int EB = (Etot + 255) / 256;
    const int NB = (N + 255) / 256;
    const int numScanBlocks = (N + 2047) / 2048;

    detect_i64<<<1, 64, 0, stream>>>((const int*)ei, flag);

    // ---- CSR build (once; shared by both layers) ----
    hipMemsetAsync(counts, 0, (size_t)N * sizeof(int), stream);
    hipMemsetAsync(fill, 0, (size_t)N * sizeof(int), stream);
    edge_hist<<<EB, 256, 0, stream>>>(ei, flag, counts, E, Etot);
    scan1<<<numScanBlocks, 256, 0, stream>>>(counts, row_ptr, bsum, N);
    scan2<<<1, 64, 0, stream>>>(bsum, numScanBlocks, &row_ptr[N]);
    scan_add<<<NB, 256, 0, stream>>>(row_ptr, bsum, N);
    edge_scatter<<<EB, 256, 0, stream>>>(ei, flag, row_ptr, fill, csr_src, E, Etot);

    const int AGG_B = (N + 3) / 4;

    // ---- layer 1 (F = 64): out = relu(agg + b1) ----
    gemm_att<64, 4><<<(N + 63) / 64, 256, 0, stream>>>(x, W1, as1, ad1, h, asn, adn, N);
    gat_aggregate<64, true, false><<<AGG_B, 256, 0, stream>>>(
        row_ptr, csr_src, asn, adn, h, b1, agg1, N);

    // ---- layer 2 (F = 40): out = log_softmax(agg + b2) ----
    gemm_att<40, 4><<<(N + 63) / 64, 256, 0, stream>>>(agg1, W2, as2, ad2, h, asn, adn, N);
    gat_aggregate<40, false, true><<<AGG_B, 256, 0, stream>>>(
        row_ptr, csr_src, asn, adn, h, b2, out, N);
}

// Round 4
// 383.204 us; speedup vs baseline: 7.7600x; 1.2212x over previous
//
#include <hip/hip_runtime.h>
#include <math.h>

#ifndef NEG_SLOPE
#define NEG_SLOPE 0.2f
#endif

// ---------------------------------------------------------------------------
// Edge-index dtype sniffer (int64 vs int32 layout). One wave, ballot.
// ---------------------------------------------------------------------------
__global__ void detect_i64(const int* __restrict__ ei, int* __restrict__ flag) {
    int lane = threadIdx.x & 63;
    int bad = 0;
    for (int j = 0; j < 4; ++j) bad |= (ei[2 * (lane * 4 + j) + 1] != 0);
    unsigned long long m = __ballot(bad);
    if (lane == 0) *flag = (m == 0ull) ? 1 : 0;
}

__device__ __forceinline__ void get_edge(const void* ei, int is64, int e, int E,
                                         int& s, int& d) {
    if (e >= E) { s = e - E; d = s; return; }   // self-loop
    if (is64) {
        const long long* p = (const long long*)ei;
        s = (int)p[e];
        d = (int)p[(long long)E + e];
    } else {
        const int* p = (const int*)ei;
        s = p[e];
        d = p[E + e];
    }
}

// ---------------------------------------------------------------------------
// Fused GEMM + attention coefficients.
// ---------------------------------------------------------------------------
template <int F, int TPR>
__global__ __launch_bounds__(256) void gemm_att(
    const float* __restrict__ A, const float* __restrict__ W,
    const float* __restrict__ avs, const float* __restrict__ avd,
    float* __restrict__ H, float* __restrict__ as_out, float* __restrict__ ad_out,
    int Nrows) {
    constexpr int K = 64;
    constexpr int R = 256 / TPR;
    constexpr int C = F / TPR;
    __shared__ float sW[K * F];
    __shared__ float sA[R * (K + 4)];
    __shared__ float sas[F], sad[F];

    const int t = threadIdx.x;
    for (int i = t; i < K * F / 4; i += 256)
        ((float4*)sW)[i] = ((const float4*)W)[i];
    for (int i = t; i < F; i += 256) { sas[i] = avs[i]; sad[i] = avd[i]; }

    const int base = blockIdx.x * R;
    for (int i = t; i < R * (K / 4); i += 256) {
        int row = i >> 4;
        int c4  = i & 15;
        float4 v = make_float4(0.f, 0.f, 0.f, 0.f);
        if (base + row < Nrows)
            v = ((const float4*)(A + (size_t)(base + row) * K))[c4];
        float* dp = &sA[row * (K + 4) + c4 * 4];
        dp[0] = v.x; dp[1] = v.y; dp[2] = v.z; dp[3] = v.w;
    }
    __syncthreads();

    const int r  = t / TPR;
    const int f0 = (t % TPR) * C;
    float acc[C];
#pragma unroll
    for (int j = 0; j < C; ++j) acc[j] = 0.f;
    const float* sa = &sA[r * (K + 4)];
#pragma unroll
    for (int k = 0; k < K; ++k) {
        float av = sa[k];
        const float* w = &sW[k * F + f0];
#pragma unroll
        for (int j = 0; j < C; ++j) acc[j] += av * w[j];
    }

    float ps = 0.f, pd = 0.f;
#pragma unroll
    for (int j = 0; j < C; ++j) { ps += acc[j] * sas[f0 + j]; pd += acc[j] * sad[f0 + j]; }
#pragma unroll
    for (int off = 1; off < TPR; off <<= 1) {
        ps += __shfl_xor(ps, off);
        pd += __shfl_xor(pd, off);
    }

    const int row = base + r;
    if (row < Nrows) {
        if ((t % TPR) == 0) { as_out[row] = ps; ad_out[row] = pd; }
        float* hp = H + (size_t)row * F + f0;
#pragma unroll
        for (int j = 0; j < C; ++j) hp[j] = acc[j];
    }
}

// ---------------------------------------------------------------------------
// CSR build: rank (histogram + slot via returning atomic, 8-way ILP)
//            -> scan -> atomic-free scatter.
// ---------------------------------------------------------------------------
#define RANK_ILP 8
__global__ __launch_bounds__(256) void edge_rank(
    const void* __restrict__ ei, const int* __restrict__ flag,
    int* __restrict__ counts, int* __restrict__ rank, int E, int Etot) {
    const int is64 = *flag;
    const int base = blockIdx.x * (256 * RANK_ILP) + threadIdx.x;
    int d[RANK_ILP], r[RANK_ILP];
    bool ok[RANK_ILP];
#pragma unroll
    for (int u = 0; u < RANK_ILP; ++u) {
        int e = base + u * 256;
        ok[u] = (e < Etot);
        int s;
        d[u] = 0;
        if (ok[u]) get_edge(ei, is64, e, E, s, d[u]);
    }
    // 8 independent returning atomics in flight per thread
#pragma unroll
    for (int u = 0; u < RANK_ILP; ++u)
        if (ok[u]) r[u] = atomicAdd(&counts[d[u]], 1);
#pragma unroll
    for (int u = 0; u < RANK_ILP; ++u) {
        int e = base + u * 256;
        if (ok[u]) rank[e] = r[u];
    }
}

__global__ __launch_bounds__(256) void scan1(
    const int* __restrict__ in, int* __restrict__ out,
    int* __restrict__ bsum, int n) {
    __shared__ int lds[256];
    const int base = blockIdx.x * 2048;
    const int t = threadIdx.x;
    int v[8];
    int s = 0;
#pragma unroll
    for (int j = 0; j < 8; ++j) {
        int idx = base + t * 8 + j;
        v[j] = (idx < n) ? in[idx] : 0;
        s += v[j];
    }
    lds[t] = s;
    __syncthreads();
    int x = s;
    for (int off = 1; off < 256; off <<= 1) {
        int y = (t >= off) ? lds[t - off] : 0;
        __syncthreads();
        x += y;
        lds[t] = x;
        __syncthreads();
    }
    if (t == 255) bsum[blockIdx.x] = x;
    int run = x - s;
#pragma unroll
    for (int j = 0; j < 8; ++j) {
        int idx = base + t * 8 + j;
        if (idx < n) out[idx] = run;
        run += v[j];
    }
}

__global__ void scan2(int* __restrict__ bsum, int nb, int* __restrict__ total_out) {
    if (threadIdx.x == 0 && blockIdx.x == 0) {
        int run = 0;
        for (int i = 0; i < nb; ++i) { int t = bsum[i]; bsum[i] = run; run += t; }
        *total_out = run;
    }
}

__global__ __launch_bounds__(256) void scan_add(
    int* __restrict__ out, const int* __restrict__ bsum_ex, int n) {
    int idx = blockIdx.x * 256 + threadIdx.x;
    if (idx < n) out[idx] += bsum_ex[idx >> 11];
}

// Atomic-free scatter: pos = row_ptr[d] + rank[e]. 4-way ILP on the random
// row_ptr read; csr write is fire-and-forget.
#define SCAT_ILP 4
__global__ __launch_bounds__(256) void edge_scatter2(
    const void* __restrict__ ei, const int* __restrict__ flag,
    const int* __restrict__ row_ptr, const int* __restrict__ rank,
    int* __restrict__ csr_src, int E, int Etot) {
    const int is64 = *flag;
    const int base = blockIdx.x * (256 * SCAT_ILP) + threadIdx.x;
    int s[SCAT_ILP], rp[SCAT_ILP], rk[SCAT_ILP];
    bool ok[SCAT_ILP];
#pragma unroll
    for (int u = 0; u < SCAT_ILP; ++u) {
        int e = base + u * 256;
        ok[u] = (e < Etot);
        if (ok[u]) {
            int d;
            get_edge(ei, is64, e, E, s[u], d);
            rp[u] = row_ptr[d];
            rk[u] = rank[e];
        }
    }
#pragma unroll
    for (int u = 0; u < SCAT_ILP; ++u)
        if (ok[u]) csr_src[rp[u] + rk[u]] = s[u];
}

// ---------------------------------------------------------------------------
// Fused per-dst GAT aggregation, one wave per dst node, single pass,
// software-pipelined gathers (8/4-deep).
// ---------------------------------------------------------------------------
template <int F, bool RELU, bool LSM>
__global__ __launch_bounds__(256) void gat_aggregate(
    const int* __restrict__ row_ptr, const int* __restrict__ csr_src,
    const float* __restrict__ asn, const float* __restrict__ adn,
    const float* __restrict__ H, const float* __restrict__ bias,
    float* __restrict__ out, int N) {
    int wid  = blockIdx.x * 4 + (threadIdx.x >> 6);
    int lane = threadIdx.x & 63;
    if (wid >= N) return;
    const int r0 = row_ptr[wid], r1 = row_ptr[wid + 1];
    const float add = adn[wid];

    float acc = 0.f;
    float Ssum = 0.f;
    for (int base = r0; base < r1; base += 64) {
        int cnt = r1 - base;
        if (cnt > 64) cnt = 64;
        int s = 0;
        float w = 0.f;
        if (lane < cnt) {
            s = csr_src[base + lane];
            float v = asn[s] + add;
            v = v > 0.f ? v : NEG_SLOPE * v;
            w = __expf(v);
        }
        Ssum += w;
        int j = 0;
        for (; j + 8 <= cnt; j += 8) {
            float wj[8], hv[8];
            const float* p[8];
#pragma unroll
            for (int u = 0; u < 8; ++u) {
                int su = __shfl(s, j + u);
                wj[u]  = __shfl(w, j + u);
                p[u]   = H + (size_t)su * F + lane;
            }
#pragma unroll
            for (int u = 0; u < 8; ++u)
                hv[u] = (F == 64 || lane < F) ? p[u][0] : 0.f;
#pragma unroll
            for (int u = 0; u < 8; ++u) acc += wj[u] * hv[u];
        }
        for (; j + 4 <= cnt; j += 4) {
            float wj[4], hv[4];
            const float* p[4];
#pragma unroll
            for (int u = 0; u < 4; ++u) {
                int su = __shfl(s, j + u);
                wj[u]  = __shfl(w, j + u);
                p[u]   = H + (size_t)su * F + lane;
            }
#pragma unroll
            for (int u = 0; u < 4; ++u)
                hv[u] = (F == 64 || lane < F) ? p[u][0] : 0.f;
#pragma unroll
            for (int u = 0; u < 4; ++u) acc += wj[u] * hv[u];
        }
        for (; j < cnt; ++j) {
            int   sj = __shfl(s, j);
            float wj = __shfl(w, j);
            float hv = (F == 64 || lane < F) ? H[(size_t)sj * F + lane] : 0.f;
            acc += wj * hv;
        }
    }
    for (int off = 32; off; off >>= 1) Ssum += __shfl_xor(Ssum, off);
    float r = acc / (Ssum + 1e-16f);

    if (LSM) {
        float val = 0.f, vv = -3.0e38f;
        if (lane < F) { val = r + bias[lane]; vv = val; }
        float mx = vv;
        for (int off = 32; off; off >>= 1) mx = fmaxf(mx, __shfl_xor(mx, off));
        float ex = (lane < F) ? __expf(val - mx) : 0.f;
        float sm = ex;
        for (int off = 32; off; off >>= 1) sm += __shfl_xor(sm, off);
        float ls = logf(sm);
        if (lane < F) out[(size_t)wid * F + lane] = val - mx - ls;
    } else {
        if (lane < F) {
            float v2 = r + bias[lane];
            if (RELU) v2 = fmaxf(v2, 0.f);
            out[(size_t)wid * F + lane] = v2;
        }
    }
}

extern "C" void kernel_launch(void* const* d_in, const int* in_sizes, int n_in,
                              void* d_out, int out_size, void* d_ws, size_t ws_size,
                              hipStream_t stream) {
    const float* x   = (const float*)d_in[0];
    const void*  ei  = d_in[1];
    const float* W1  = (const float*)d_in[2];
    const float* as1 = (const float*)d_in[3];
    const float* ad1 = (const float*)d_in[4];
    const float* b1  = (const float*)d_in[5];
    const float* W2  = (const float*)d_in[6];
    const float* as2 = (const float*)d_in[7];
    const float* ad2 = (const float*)d_in[8];
    const float* b2  = (const float*)d_in[9];
    float* out = (float*)d_out;

    const int N    = in_sizes[0] / 64;
    const int E    = in_sizes[1] / 2;
    const int Etot = E + N;

    float* ws = (float*)d_ws;
    float* h    = ws;              ws += (size_t)N * 64;
    float* agg1 = ws;              ws += (size_t)N * 64;
    float* asn  = ws;              ws += N;
    float* adn  = ws;              ws += N;
    int* counts = (int*)ws;        ws += N;
    int* row_ptr = (int*)ws;       ws += N + 1;
    int* rank   = (int*)ws;        ws += Etot;
    int* csr_src = (int*)ws;       ws += Etot;
    int* bsum   = (int*)ws;        ws += 256;
    int* flag   = (int*)ws;

    const int NB = (N + 255) / 256;
    const int numScanBlocks = (N + 2047) / 2048;

    detect_i64<<<1, 64, 0, stream>>>((const int*)ei, flag);

    // ---- CSR build (once; shared by both layers) ----
    hipMemsetAsync(counts, 0, (size_t)N * sizeof(int), stream);
    {
        int rb = (Etot + 256 * RANK_ILP - 1) / (256 * RANK_ILP);
        edge_rank<<<rb, 256, 0, stream>>>(ei, flag, counts, rank, E, Etot);
    }
    scan1<<<numScanBlocks, 256, 0, stream>>>(counts, row_ptr, bsum, N);
    scan2<<<1, 64, 0, stream>>>(bsum, numScanBlocks, &row_ptr[N]);
    scan_add<<<NB, 256, 0, stream>>>(row_ptr, bsum, N);
    {
        int sb = (Etot + 256 * SCAT_ILP - 1) / (256 * SCAT_ILP);
        edge_scatter2<<<sb, 256, 0, stream>>>(ei, flag, row_ptr, rank, csr_src, E, Etot);
    }

    const int AGG_B = (N + 3) / 4;

    // ---- layer 1 (F = 64): out = relu(agg + b1) ----
    gemm_att<64, 4><<<(N + 63) / 64, 256, 0, stream>>>(x, W1, as1, ad1, h, asn, adn, N);
    gat_aggregate<64, true, false><<<AGG_B, 256, 0, stream>>>(
        row_ptr, csr_src, asn, adn, h, b1, agg1, N);

    // ---- layer 2 (F = 40): out = log_softmax(agg + b2) ----
    gemm_att<40, 4><<<(N + 63) / 64, 256, 0, stream>>>(agg1, W2, as2, ad2, h, asn, adn, N);
    gat_aggregate<40, false, true><<<AGG_B, 256, 0, stream>>>(
        row_ptr, csr_src, asn, adn, h, b2, out, N);
}

// Round 5
// 371.997 us; speedup vs baseline: 7.9938x; 1.0301x over previous
//
#include <hip/hip_runtime.h>
#include <math.h>

#ifndef NEG_SLOPE
#define NEG_SLOPE 0.2f
#endif

// ---------------------------------------------------------------------------
// Edge-index dtype sniffer (int64 vs int32 layout). One wave, ballot.
// ---------------------------------------------------------------------------
__global__ void detect_i64(const int* __restrict__ ei, int* __restrict__ flag) {
    int lane = threadIdx.x & 63;
    int bad = 0;
    for (int j = 0; j < 4; ++j) bad |= (ei[2 * (lane * 4 + j) + 1] != 0);
    unsigned long long m = __ballot(bad);
    if (lane == 0) *flag = (m == 0ull) ? 1 : 0;
}

__device__ __forceinline__ void get_edge(const void* ei, int is64, int e, int E,
                                         int& s, int& d) {
    if (e >= E) { s = e - E; d = s; return; }   // self-loop
    if (is64) {
        const long long* p = (const long long*)ei;
        s = (int)p[e];
        d = (int)p[(long long)E + e];
    } else {
        const int* p = (const int*)ei;
        s = p[e];
        d = p[E + e];
    }
}

// ---------------------------------------------------------------------------
// Fused GEMM + attention coefficients.
// ---------------------------------------------------------------------------
template <int F, int TPR>
__global__ __launch_bounds__(256) void gemm_att(
    const float* __restrict__ A, const float* __restrict__ W,
    const float* __restrict__ avs, const float* __restrict__ avd,
    float* __restrict__ H, float* __restrict__ as_out, float* __restrict__ ad_out,
    int Nrows) {
    constexpr int K = 64;
    constexpr int R = 256 / TPR;
    constexpr int C = F / TPR;
    __shared__ float sW[K * F];
    __shared__ float sA[R * (K + 4)];
    __shared__ float sas[F], sad[F];

    const int t = threadIdx.x;
    for (int i = t; i < K * F / 4; i += 256)
        ((float4*)sW)[i] = ((const float4*)W)[i];
    for (int i = t; i < F; i += 256) { sas[i] = avs[i]; sad[i] = avd[i]; }

    const int base = blockIdx.x * R;
    for (int i = t; i < R * (K / 4); i += 256) {
        int row = i >> 4;
        int c4  = i & 15;
        float4 v = make_float4(0.f, 0.f, 0.f, 0.f);
        if (base + row < Nrows)
            v = ((const float4*)(A + (size_t)(base + row) * K))[c4];
        float* dp = &sA[row * (K + 4) + c4 * 4];
        dp[0] = v.x; dp[1] = v.y; dp[2] = v.z; dp[3] = v.w;
    }
    __syncthreads();

    const int r  = t / TPR;
    const int f0 = (t % TPR) * C;
    float acc[C];
#pragma unroll
    for (int j = 0; j < C; ++j) acc[j] = 0.f;
    const float* sa = &sA[r * (K + 4)];
#pragma unroll
    for (int k = 0; k < K; ++k) {
        float av = sa[k];
        const float* w = &sW[k * F + f0];
#pragma unroll
        for (int j = 0; j < C; ++j) acc[j] += av * w[j];
    }

    float ps = 0.f, pd = 0.f;
#pragma unroll
    for (int j = 0; j < C; ++j) { ps += acc[j] * sas[f0 + j]; pd += acc[j] * sad[f0 + j]; }
#pragma unroll
    for (int off = 1; off < TPR; off <<= 1) {
        ps += __shfl_xor(ps, off);
        pd += __shfl_xor(pd, off);
    }

    const int row = base + r;
    if (row < Nrows) {
        if ((t % TPR) == 0) { as_out[row] = ps; ad_out[row] = pd; }
        float* hp = H + (size_t)row * F + f0;
#pragma unroll
        for (int j = 0; j < C; ++j) hp[j] = acc[j];
    }
}

// ---------------------------------------------------------------------------
// CSR build: rank (returning atomic, 8-way ILP) -> scan -> atomic-free scatter.
// ---------------------------------------------------------------------------
#define RANK_ILP 8
__global__ __launch_bounds__(256) void edge_rank(
    const void* __restrict__ ei, const int* __restrict__ flag,
    int* __restrict__ counts, int* __restrict__ rank, int E, int Etot) {
    const int is64 = *flag;
    const int base = blockIdx.x * (256 * RANK_ILP) + threadIdx.x;
    int d[RANK_ILP], r[RANK_ILP];
    bool ok[RANK_ILP];
#pragma unroll
    for (int u = 0; u < RANK_ILP; ++u) {
        int e = base + u * 256;
        ok[u] = (e < Etot);
        int s;
        d[u] = 0;
        if (ok[u]) get_edge(ei, is64, e, E, s, d[u]);
    }
#pragma unroll
    for (int u = 0; u < RANK_ILP; ++u)
        if (ok[u]) r[u] = atomicAdd(&counts[d[u]], 1);
#pragma unroll
    for (int u = 0; u < RANK_ILP; ++u) {
        int e = base + u * 256;
        if (ok[u]) rank[e] = r[u];
    }
}

__global__ __launch_bounds__(256) void scan1(
    const int* __restrict__ in, int* __restrict__ out,
    int* __restrict__ bsum, int n) {
    __shared__ int lds[256];
    const int base = blockIdx.x * 2048;
    const int t = threadIdx.x;
    int v[8];
    int s = 0;
#pragma unroll
    for (int j = 0; j < 8; ++j) {
        int idx = base + t * 8 + j;
        v[j] = (idx < n) ? in[idx] : 0;
        s += v[j];
    }
    lds[t] = s;
    __syncthreads();
    int x = s;
    for (int off = 1; off < 256; off <<= 1) {
        int y = (t >= off) ? lds[t - off] : 0;
        __syncthreads();
        x += y;
        lds[t] = x;
        __syncthreads();
    }
    if (t == 255) bsum[blockIdx.x] = x;
    int run = x - s;
#pragma unroll
    for (int j = 0; j < 8; ++j) {
        int idx = base + t * 8 + j;
        if (idx < n) out[idx] = run;
        run += v[j];
    }
}

__global__ void scan2(int* __restrict__ bsum, int nb, int* __restrict__ total_out) {
    if (threadIdx.x == 0 && blockIdx.x == 0) {
        int run = 0;
        for (int i = 0; i < nb; ++i) { int t = bsum[i]; bsum[i] = run; run += t; }
        *total_out = run;
    }
}

__global__ __launch_bounds__(256) void scan_add(
    int* __restrict__ out, const int* __restrict__ bsum_ex, int n) {
    int idx = blockIdx.x * 256 + threadIdx.x;
    if (idx < n) out[idx] += bsum_ex[idx >> 11];
}

#define SCAT_ILP 4
__global__ __launch_bounds__(256) void edge_scatter2(
    const void* __restrict__ ei, const int* __restrict__ flag,
    const int* __restrict__ row_ptr, const int* __restrict__ rank,
    int* __restrict__ csr_src, int E, int Etot) {
    const int is64 = *flag;
    const int base = blockIdx.x * (256 * SCAT_ILP) + threadIdx.x;
    int s[SCAT_ILP], rp[SCAT_ILP], rk[SCAT_ILP];
    bool ok[SCAT_ILP];
#pragma unroll
    for (int u = 0; u < SCAT_ILP; ++u) {
        int e = base + u * 256;
        ok[u] = (e < Etot);
        if (ok[u]) {
            int d;
            get_edge(ei, is64, e, E, s[u], d);
            rp[u] = row_ptr[d];
            rk[u] = rank[e];
        }
    }
#pragma unroll
    for (int u = 0; u < SCAT_ILP; ++u)
        if (ok[u]) csr_src[rp[u] + rk[u]] = s[u];
}

// ---------------------------------------------------------------------------
// Fused per-dst GAT aggregation, one wave per dst node.
// Wave = 4 groups x 16 lanes; each group handles one edge per step, each lane
// loads a float4 of the src row (global_load_dwordx4). 4 edges per load-issue
// step, 16-edge main block => 4 dwordx4 in flight. Group-partial float4
// accumulators reduced via shfl_xor(16,32) in the epilogue.
// ---------------------------------------------------------------------------
template <int F, bool RELU, bool LSM>
__global__ __launch_bounds__(256) void gat_aggregate(
    const int* __restrict__ row_ptr, const int* __restrict__ csr_src,
    const float* __restrict__ asn, const float* __restrict__ adn,
    const float* __restrict__ H, const float* __restrict__ bias,
    float* __restrict__ out, int N) {
    constexpr int NQ = F / 4;             // quads per row: 16 (F=64), 10 (F=40)
    int wid  = blockIdx.x * 4 + (threadIdx.x >> 6);
    int lane = threadIdx.x & 63;
    if (wid >= N) return;
    const int grp = lane >> 4;            // edge slot within a 4-edge step
    const int q   = lane & 15;            // quad within row
    const int qc  = (q < NQ) ? q : NQ - 1;        // clamped (uniform loads)
    const float qmask = (q < NQ) ? 1.f : 0.f;
    const int r0 = row_ptr[wid], r1 = row_ptr[wid + 1];
    const float add = adn[wid];

    float4 acc = make_float4(0.f, 0.f, 0.f, 0.f);
    float Ssum = 0.f;
    for (int base = r0; base < r1; base += 64) {
        int cnt = r1 - base;
        if (cnt > 64) cnt = 64;
        int s = 0;
        float w = 0.f;
        if (lane < cnt) {
            s = csr_src[base + lane];
            float v = asn[s] + add;
            v = v > 0.f ? v : NEG_SLOPE * v;
            w = __expf(v);
        }
        Ssum += w;

        int jj = 0;
        for (; jj + 16 <= cnt; jj += 16) {       // main: 16 edges, 4 loads in flight
            int se[4]; float we[4]; float4 hv[4];
#pragma unroll
            for (int k = 0; k < 4; ++k) {
                int e = jj + 4 * k + grp;
                se[k] = __shfl(s, e);
                we[k] = __shfl(w, e) * qmask;
            }
#pragma unroll
            for (int k = 0; k < 4; ++k)
                hv[k] = ((const float4*)(H + (size_t)se[k] * F))[qc];
#pragma unroll
            for (int k = 0; k < 4; ++k) {
                acc.x += we[k] * hv[k].x;
                acc.y += we[k] * hv[k].y;
                acc.z += we[k] * hv[k].z;
                acc.w += we[k] * hv[k].w;
            }
        }
        for (; jj < cnt; jj += 4) {              // tail: 4 edges/step, masked
            int e  = jj + grp;
            int ec = e & 63;
            int   se = __shfl(s, ec);
            float we = __shfl(w, ec) * qmask;
            if (e >= cnt) we = 0.f;
            float4 hv = ((const float4*)(H + (size_t)se * F))[qc];
            acc.x += we * hv.x;
            acc.y += we * hv.y;
            acc.z += we * hv.z;
            acc.w += we * hv.w;
        }
    }
#pragma unroll
    for (int off = 32; off; off >>= 1) Ssum += __shfl_xor(Ssum, off);
#pragma unroll
    for (int off = 16; off <= 32; off <<= 1) {   // reduce across the 4 groups
        acc.x += __shfl_xor(acc.x, off);
        acc.y += __shfl_xor(acc.y, off);
        acc.z += __shfl_xor(acc.z, off);
        acc.w += __shfl_xor(acc.w, off);
    }
    const float inv = 1.f / (Ssum + 1e-16f);
    float4 r4 = make_float4(acc.x * inv, acc.y * inv, acc.z * inv, acc.w * inv);

    if (LSM) {
        float4 b4 = ((const float4*)bias)[qc];
        float4 val = make_float4(r4.x + b4.x, r4.y + b4.y, r4.z + b4.z, r4.w + b4.w);
        float mx = (q < NQ) ? fmaxf(fmaxf(val.x, val.y), fmaxf(val.z, val.w)) : -3.0e38f;
#pragma unroll
        for (int off = 1; off <= 8; off <<= 1) mx = fmaxf(mx, __shfl_xor(mx, off));
        float sm = 0.f;
        if (q < NQ)
            sm = __expf(val.x - mx) + __expf(val.y - mx) +
                 __expf(val.z - mx) + __expf(val.w - mx);
#pragma unroll
        for (int off = 1; off <= 8; off <<= 1) sm += __shfl_xor(sm, off);
        float ls = logf(sm) + mx;
        if (grp == 0 && q < NQ) {
            float4 o = make_float4(val.x - ls, val.y - ls, val.z - ls, val.w - ls);
            ((float4*)(out + (size_t)wid * F))[q] = o;
        }
    } else {
        if (grp == 0 && q < NQ) {
            float4 b4 = ((const float4*)bias)[q];
            float4 o = make_float4(r4.x + b4.x, r4.y + b4.y, r4.z + b4.z, r4.w + b4.w);
            if (RELU) {
                o.x = fmaxf(o.x, 0.f); o.y = fmaxf(o.y, 0.f);
                o.z = fmaxf(o.z, 0.f); o.w = fmaxf(o.w, 0.f);
            }
            ((float4*)(out + (size_t)wid * F))[q] = o;
        }
    }
}

extern "C" void kernel_launch(void* const* d_in, const int* in_sizes, int n_in,
                              void* d_out, int out_size, void* d_ws, size_t ws_size,
                              hipStream_t stream) {
    const float* x   = (const float*)d_in[0];
    const void*  ei  = d_in[1];
    const float* W1  = (const float*)d_in[2];
    const float* as1 = (const float*)d_in[3];
    const float* ad1 = (const float*)d_in[4];
    const float* b1  = (const float*)d_in[5];
    const float* W2  = (const float*)d_in[6];
    const float* as2 = (const float*)d_in[7];
    const float* ad2 = (const float*)d_in[8];
    const float* b2  = (const float*)d_in[9];
    float* out = (float*)d_out;

    const int N    = in_sizes[0] / 64;
    const int E    = in_sizes[1] / 2;
    const int Etot = E + N;

    float* ws = (float*)d_ws;
    float* h    = ws;              ws += (size_t)N * 64;
    float* agg1 = ws;              ws += (size_t)N * 64;
    float* asn  = ws;              ws += N;
    float* adn  = ws;              ws += N;
    int* counts = (int*)ws;        ws += N;
    int* row_ptr = (int*)ws;       ws += N + 1;
    int* rank   = (int*)ws;        ws += Etot;
    int* csr_src = (int*)ws;       ws += Etot;
    int* bsum   = (int*)ws;        ws += 256;
    int* flag   = (int*)ws;

    const int NB = (N + 255) / 256;
    const int numScanBlocks = (N + 2047) / 2048;

    detect_i64<<<1, 64, 0, stream>>>((const int*)ei, flag);

    // ---- CSR build (once; shared by both layers) ----
    hipMemsetAsync(counts, 0, (size_t)N * sizeof(int), stream);
    {
        int rb = (Etot + 256 * RANK_ILP - 1) / (256 * RANK_ILP);
        edge_rank<<<rb, 256, 0, stream>>>(ei, flag, counts, rank, E, Etot);
    }
    scan1<<<numScanBlocks, 256, 0, stream>>>(counts, row_ptr, bsum, N);
    scan2<<<1, 64, 0, stream>>>(bsum, numScanBlocks, &row_ptr[N]);
    scan_add<<<NB, 256, 0, stream>>>(row_ptr, bsum, N);
    {
        int sb = (Etot + 256 * SCAT_ILP - 1) / (256 * SCAT_ILP);
        edge_scatter2<<<sb, 256, 0, stream>>>(ei, flag, row_ptr, rank, csr_src, E, Etot);
    }

    const int AGG_B = (N + 3) / 4;

    // ---- layer 1 (F = 64): out = relu(agg + b1) ----
    gemm_att<64, 4><<<(N + 63) / 64, 256, 0, stream>>>(x, W1, as1, ad1, h, asn, adn, N);
    gat_aggregate<64, true, false><<<AGG_B, 256, 0, stream>>>(
        row_ptr, csr_src, asn, adn, h, b1, agg1, N);

    // ---- layer 2 (F = 40): out = log_softmax(agg + b2) ----
    gemm_att<40, 4><<<(N + 63) / 64, 256, 0, stream>>>(agg1, W2, as2, ad2, h, asn, adn, N);
    gat_aggregate<40, false, true><<<AGG_B, 256, 0, stream>>>(
        row_ptr, csr_src, asn, adn, h, b2, out, N);
}